// Round 2
// baseline (606.223 us; speedup 1.0000x reference)
//
#include <hip/hip_runtime.h>

// RGAT 2-layer + BN/ELU + head for MI355X (gfx950).
// Float inputs may be bf16 OR fp32 (runtime-detected); ints are int32.
// Internal compute fp32 in workspace. Output stored in detected float width.

typedef unsigned short ushort_t;
typedef unsigned int uint_t;

#define NEG_SLOPE 0.2f
#define BN_EPS 1e-5f

__device__ __forceinline__ float bf2f(ushort_t u) {
    return __uint_as_float(((uint_t)u) << 16);
}
__device__ __forceinline__ ushort_t f2bf(float f) {
    uint_t x = __float_as_uint(f);
    x += 0x7FFFu + ((x >> 16) & 1u);   // round-to-nearest-even
    return (ushort_t)(x >> 16);
}
// generic float load: bf16 (isb=1) or fp32 (isb=0)
__device__ __forceinline__ float loadf(const void* p, int i, int isb) {
    return isb ? bf2f(((const ushort_t*)p)[i]) : ((const float*)p)[i];
}

// ---------------- input dtype detection ----------------
// Sample 256 uint32 words of node_emb. bf16 storage: low ushort is a bf16 of
// ~N(0,1) -> exponent field in [96,150] nearly always. fp32 storage: low 16
// bits are uniform mantissa bits -> ~21% in range. (fp32 storage of values
// that happen to be bf16-rounded gives low ushort == 0 -> also flag=0.)
__global__ void k_detect(const uint_t* __restrict__ x, int* __restrict__ flag) {
    int t = threadIdx.x;
    uint_t u = x[t * 37];
    uint_t lo_exp = (u >> 7) & 0xFF;
    int like = (lo_exp >= 96 && lo_exp <= 150) ? 1 : 0;
    __shared__ int cnt;
    if (t == 0) cnt = 0;
    __syncthreads();
    atomicAdd(&cnt, like);
    __syncthreads();
    if (t == 0) flag[0] = (cnt > 192) ? 1 : 0;
}

// ---------------- CSR build ----------------
__global__ void k_count(const int* __restrict__ ei, int* __restrict__ deg, int E) {
    int e = blockIdx.x * 256 + threadIdx.x;
    if (e < E) atomicAdd(&deg[ei[E + e]], 1);
}

__global__ void k_scan1(const int* __restrict__ deg, int* __restrict__ part,
                        int* __restrict__ bsum, int N) {
    __shared__ int s[256];
    int t = threadIdx.x;
    int i = blockIdx.x * 256 + t;
    int v = (i < N) ? deg[i] : 0;
    s[t] = v; __syncthreads();
    for (int off = 1; off < 256; off <<= 1) {
        int x = (t >= off) ? s[t - off] : 0;
        __syncthreads();
        s[t] += x;
        __syncthreads();
    }
    if (i < N) part[i] = s[t] - v;           // exclusive within block
    if (t == 255) bsum[blockIdx.x] = s[255]; // block total
}

__global__ void k_scan2(const int* __restrict__ bsum, int* __restrict__ boff, int NB) {
    __shared__ int s[256];
    int t = threadIdx.x;
    int v = (t < NB) ? bsum[t] : 0;
    s[t] = v; __syncthreads();
    for (int off = 1; off < 256; off <<= 1) {
        int x = (t >= off) ? s[t - off] : 0;
        __syncthreads();
        s[t] += x;
        __syncthreads();
    }
    if (t < NB) boff[t] = s[t] - v;
}

__global__ void k_scan3(int* __restrict__ row, int* __restrict__ cursor,
                        const int* __restrict__ boff, int N, int E) {
    int i = blockIdx.x * 256 + threadIdx.x;
    if (i < N) {
        int v = row[i] + boff[blockIdx.x];
        row[i] = v;
        cursor[i] = v;
    }
    if (i == 0) row[N] = E;
}

__global__ void k_scatter(const int* __restrict__ ei, const int* __restrict__ et,
                          const void* __restrict__ ea, const int* __restrict__ flag,
                          int* __restrict__ cursor,
                          int* __restrict__ pbuf, float* __restrict__ fbuf, int E) {
    int isb = flag[0];
    int e = blockIdx.x * 256 + threadIdx.x;
    if (e < E) {
        int d = ei[E + e];
        int pos = atomicAdd(&cursor[d], 1);
        pbuf[pos] = ei[e] | (et[e] << 20);   // src < 2^20, etype < 4
        fbuf[pos] = loadf(ea, e, isb);
    }
}

// ---------------- weight pre-transpose to fp32 [f][r*O+o] ----------------
__global__ void k_convw(const void* __restrict__ W1, const void* __restrict__ W2,
                        const int* __restrict__ flag,
                        float* __restrict__ Wf1, float* __restrict__ Wf2) {
    int isb = flag[0];
    int t = threadIdx.x;
    for (int idx = t; idx < 128 * 60; idx += 256) {
        int f = idx / 60, j = idx % 60, r = j / 15, o = j % 15;
        Wf1[idx] = loadf(W1, (r * 128 + f) * 15 + o, isb);
    }
    for (int idx = t; idx < 15 * 40; idx += 256) {
        int f = idx / 40, j = idx % 40, r = j / 10, o = j % 10;
        Wf2[idx] = loadf(W2, (r * 15 + f) * 10 + o, isb);
    }
}

// ---------------- layer-1 transform: xt1[n, r*15+o], dotq/dotk[n,r] ----------------
__global__ __launch_bounds__(256) void k_t1(const void* __restrict__ xin,
                                            const float* __restrict__ Wf,
                                            const void* __restrict__ qb,
                                            const void* __restrict__ kb,
                                            const int* __restrict__ flag,
                                            float* __restrict__ xt,
                                            float* __restrict__ dq,
                                            float* __restrict__ dk, int N) {
    int isb = flag[0];
    int n = blockIdx.x * 256 + threadIdx.x;
    if (n >= N) return;
    float acc[60];
#pragma unroll
    for (int j = 0; j < 60; ++j) acc[j] = 0.f;
    if (isb) {
        const uint4* x4 = reinterpret_cast<const uint4*>((const ushort_t*)xin + (size_t)n * 128);
        for (int c = 0; c < 16; ++c) {       // 16 chunks x 8 bf16
            uint4 u = x4[c];
            uint_t w[4] = {u.x, u.y, u.z, u.w};
#pragma unroll
            for (int h = 0; h < 4; ++h) {
                float x0 = __uint_as_float(w[h] << 16);
                float x1 = __uint_as_float(w[h] & 0xFFFF0000u);
                const float* wp = Wf + (c * 8 + h * 2) * 60;
#pragma unroll
                for (int o = 0; o < 60; ++o) acc[o] += x0 * wp[o];
#pragma unroll
                for (int o = 0; o < 60; ++o) acc[o] += x1 * wp[60 + o];
            }
        }
    } else {
        const float4* x4 = reinterpret_cast<const float4*>((const float*)xin + (size_t)n * 128);
        for (int c = 0; c < 32; ++c) {       // 32 chunks x 4 fp32
            float4 u = x4[c];
            const float* wp = Wf + c * 4 * 60;
#pragma unroll
            for (int o = 0; o < 60; ++o) acc[o] += u.x * wp[o];
#pragma unroll
            for (int o = 0; o < 60; ++o) acc[o] += u.y * wp[60 + o];
#pragma unroll
            for (int o = 0; o < 60; ++o) acc[o] += u.z * wp[120 + o];
#pragma unroll
            for (int o = 0; o < 60; ++o) acc[o] += u.w * wp[180 + o];
        }
    }
    float qf[15], kf[15];
#pragma unroll
    for (int o = 0; o < 15; ++o) { qf[o] = loadf(qb, o, isb); kf[o] = loadf(kb, o, isb); }
#pragma unroll
    for (int r = 0; r < 4; ++r) {
        float a = 0.f, b = 0.f;
#pragma unroll
        for (int o = 0; o < 15; ++o) { a += acc[r * 15 + o] * qf[o]; b += acc[r * 15 + o] * kf[o]; }
        dq[n * 4 + r] = a;
        dk[n * 4 + r] = b;
    }
#pragma unroll
    for (int j = 0; j < 60; ++j) xt[(size_t)n * 60 + j] = acc[j];
}

// ---------------- layer-2 transform: BN1+ELU fused, then xt2/dotq2/dotk2 ----------------
__global__ __launch_bounds__(256) void k_t2(const float* __restrict__ in,
                                            const float* __restrict__ stats,
                                            const void* __restrict__ g,
                                            const void* __restrict__ beta,
                                            const float* __restrict__ Wf,
                                            const void* __restrict__ qb,
                                            const void* __restrict__ kb,
                                            const int* __restrict__ flag,
                                            float* __restrict__ xt,
                                            float* __restrict__ dq,
                                            float* __restrict__ dk, int N) {
    int isb = flag[0];
    int n = blockIdx.x * 256 + threadIdx.x;
    if (n >= N) return;
    float invN = 1.f / (float)N;
    float v[15];
#pragma unroll
    for (int c = 0; c < 15; ++c) {
        float mean = stats[c] * invN;
        float var = stats[16 + c] * invN - mean * mean;
        float inv = rsqrtf(var + BN_EPS);
        float h = (in[(size_t)n * 15 + c] - mean) * inv * loadf(g, c, isb) + loadf(beta, c, isb);
        v[c] = h > 0.f ? h : expm1f(h);  // ELU
    }
    float acc[40];
#pragma unroll
    for (int j = 0; j < 40; ++j) acc[j] = 0.f;
#pragma unroll
    for (int f = 0; f < 15; ++f) {
        const float* wp = Wf + f * 40;
#pragma unroll
        for (int o = 0; o < 40; ++o) acc[o] += v[f] * wp[o];
    }
    float qf[10], kf[10];
#pragma unroll
    for (int o = 0; o < 10; ++o) { qf[o] = loadf(qb, o, isb); kf[o] = loadf(kb, o, isb); }
#pragma unroll
    for (int r = 0; r < 4; ++r) {
        float a = 0.f, b = 0.f;
#pragma unroll
        for (int o = 0; o < 10; ++o) { a += acc[r * 10 + o] * qf[o]; b += acc[r * 10 + o] * kf[o]; }
        dq[n * 4 + r] = a;
        dk[n * 4 + r] = b;
    }
#pragma unroll
    for (int j = 0; j < 40; ++j) xt[(size_t)n * 40 + j] = acc[j];
}

// ---------------- per-node gather: softmax + weighted aggregation ----------------
// One 64-lane wave per node. Phase A: online softmax (m,s) + butterfly combine.
// Phase B: 4 edge-groups x 16 channel-lanes, coalesced 60B/40B xt gathers.
template <int O>
__global__ __launch_bounds__(256) void k_gather(const int* __restrict__ row_ptr,
                                                const int* __restrict__ pbuf,
                                                const float* __restrict__ fbuf,
                                                const float* __restrict__ dq,
                                                const float* __restrict__ dk,
                                                const float* __restrict__ xt,
                                                const void* __restrict__ Web,
                                                const void* __restrict__ eb,
                                                const void* __restrict__ bb,
                                                const int* __restrict__ flag,
                                                float* __restrict__ out, int N) {
    int isb = flag[0];
    int lane = threadIdx.x & 63;
    int n = blockIdx.x * 4 + (threadIdx.x >> 6);
    if (n >= N) return;
    float c = 0.f;  // scalar (We . e) — edge-attr coefficient
#pragma unroll
    for (int o = 0; o < O; ++o) c += loadf(Web, o, isb) * loadf(eb, o, isb);
    int start = row_ptr[n], end = row_ptr[n + 1];

    // Phase A: online softmax over this node's incoming edges
    float m = -1e30f, s = 0.f;
    for (int p = start + lane; p < end; p += 64) {
        int pk = pbuf[p];
        int sr = pk & 0xFFFFF, et = pk >> 20;
        float a = dq[n * 4 + et] + dk[sr * 4 + et] + c * fbuf[p];
        a = a > 0.f ? a : NEG_SLOPE * a;
        float mn = fmaxf(m, a);
        s = s * __expf(m - mn) + __expf(a - mn);
        m = mn;
    }
#pragma unroll
    for (int off = 32; off; off >>= 1) {
        float m2 = __shfl_xor(m, off, 64);
        float s2 = __shfl_xor(s, off, 64);
        float mn = fmaxf(m, m2);
        s = s * __expf(m - mn) + s2 * __expf(m2 - mn);
        m = mn;
    }
    float inv = 1.f / (s + 1e-16f);

    // Phase B: weighted aggregation, channels across lanes
    int g = lane >> 4, ch = lane & 15;
    float acc = 0.f;
    for (int p = start + g; p < end; p += 4) {
        int pk = pbuf[p];
        int sr = pk & 0xFFFFF, et = pk >> 20;
        float a = dq[n * 4 + et] + dk[sr * 4 + et] + c * fbuf[p];
        a = a > 0.f ? a : NEG_SLOPE * a;
        float coeff = __expf(a - m) * inv;
        if (ch < O) acc += coeff * xt[(size_t)(sr * 4 + et) * O + ch];
    }
    acc += __shfl_xor(acc, 16, 64);
    acc += __shfl_xor(acc, 32, 64);
    if (lane < O) out[(size_t)n * O + lane] = acc + loadf(bb, lane, isb);
}

// ---------------- BN batch statistics (sum, sumsq per channel) ----------------
template <int C>
__global__ __launch_bounds__(256) void k_bnstats(const float* __restrict__ in,
                                                 float* __restrict__ S, int N) {
    int t = threadIdx.x;
    int ch = t & 15, rg = t >> 4;  // 16 row-groups x 16 channel-lanes
    float s1 = 0.f, s2 = 0.f;
    int row0 = blockIdx.x * 256;
    int rowEnd = row0 + 256;
    if (rowEnd > N) rowEnd = N;
    if (ch < C) {
        for (int r = row0 + rg; r < rowEnd; r += 16) {
            float v = in[(size_t)r * C + ch];
            s1 += v;
            s2 += v * v;
        }
    }
    __shared__ float L1[256], L2[256];
    L1[t] = s1; L2[t] = s2;
    __syncthreads();
    for (int k = 128; k >= 16; k >>= 1) {
        if (t < k) { L1[t] += L1[t + k]; L2[t] += L2[t + k]; }
        __syncthreads();
    }
    if (t < C) {
        atomicAdd(&S[t], L1[t]);
        atomicAdd(&S[16 + t], L2[t]);
    }
}

// ---------------- BN2 + ELU + head, bf16-or-fp32 output ----------------
__global__ __launch_bounds__(256) void k_head(const float* __restrict__ in,
                                              const float* __restrict__ stats,
                                              const void* __restrict__ g,
                                              const void* __restrict__ beta,
                                              const void* __restrict__ wh,
                                              const void* __restrict__ bh,
                                              const int* __restrict__ flag,
                                              void* __restrict__ out, int N) {
    int isb = flag[0];
    int n = blockIdx.x * 256 + threadIdx.x;
    if (n >= N) return;
    float invN = 1.f / (float)N;
    float r = loadf(bh, 0, isb);
#pragma unroll
    for (int c = 0; c < 10; ++c) {
        float mean = stats[c] * invN;
        float var = stats[16 + c] * invN - mean * mean;
        float inv = rsqrtf(var + BN_EPS);
        float h = (in[(size_t)n * 10 + c] - mean) * inv * loadf(g, c, isb) + loadf(beta, c, isb);
        float e = h > 0.f ? h : expm1f(h);
        r += e * loadf(wh, c, isb);
    }
    if (isb) ((ushort_t*)out)[n] = f2bf(r);
    else     ((float*)out)[n] = r;
}

extern "C" void kernel_launch(void* const* d_in, const int* in_sizes, int n_in,
                              void* d_out, int out_size, void* d_ws, size_t ws_size,
                              hipStream_t stream) {
    const void* node_emb  = d_in[0];
    const int*  edge_index = (const int*)d_in[1];
    const int*  edge_types = (const int*)d_in[2];
    const void* edge_attr = d_in[3];
    const void* W1  = d_in[4];
    const void* q1  = d_in[5];
    const void* k1  = d_in[6];
    const void* e1  = d_in[7];
    const void* We1 = d_in[8];
    const void* b1  = d_in[9];
    const void* W2  = d_in[10];
    const void* q2  = d_in[11];
    const void* k2  = d_in[12];
    const void* e2  = d_in[13];
    const void* We2 = d_in[14];
    const void* b2  = d_in[15];
    const void* g1  = d_in[16];
    const void* beta1 = d_in[17];
    const void* g2  = d_in[18];
    const void* beta2 = d_in[19];
    const void* w_head = d_in[20];
    const void* b_head = d_in[21];

    int N = in_sizes[0] / 128;
    int E = in_sizes[1] / 2;

    char* ws = (char*)d_ws;
    size_t off = 0;
    auto alloc = [&](size_t bytes) -> void* {
        void* p = ws + off;
        off = (off + bytes + 255) & ~(size_t)255;
        return p;
    };
    int*   row_ptr = (int*)alloc(((size_t)N + 1) * 4);
    int*   deg     = (int*)alloc((size_t)N * 4);
    int*   cursor  = (int*)alloc((size_t)N * 4);
    int*   bsum    = (int*)alloc(256 * 4);
    int*   boff    = (int*)alloc(256 * 4);
    int*   dflag   = (int*)alloc(256);
    int*   pbuf    = (int*)alloc((size_t)E * 4);
    float* fbuf    = (float*)alloc((size_t)E * 4);
    float* xt1     = (float*)alloc((size_t)N * 60 * 4);   // layer2 xt overlays (N*40*4)
    float* dq1     = (float*)alloc((size_t)N * 16);
    float* dk1     = (float*)alloc((size_t)N * 16);
    float* out1    = (float*)alloc((size_t)N * 15 * 4);   // out2 overlays (N*10*4)
    float* stats1  = (float*)alloc(128);
    float* stats2  = (float*)alloc(128);
    float* Wf1     = (float*)alloc(7680 * 4);
    float* Wf2     = (float*)alloc(600 * 4);
    // overlays (lifetimes disjoint):
    float* xt2  = xt1;
    float* dq2  = dq1;
    float* dk2  = dk1;
    float* out2 = out1;

    hipMemsetAsync(deg, 0, (size_t)N * 4, stream);
    hipMemsetAsync(stats1, 0, 128, stream);
    hipMemsetAsync(stats2, 0, 128, stream);

    int NB_N = (N + 255) / 256;   // 196 for N=50000 (must be <= 256 for scan2)
    int NB_E = (E + 255) / 256;
    int NB_G = (N + 3) / 4;

    k_detect<<<1, 256, 0, stream>>>((const uint_t*)node_emb, dflag);
    k_count<<<NB_E, 256, 0, stream>>>(edge_index, deg, E);
    k_scan1<<<NB_N, 256, 0, stream>>>(deg, row_ptr, bsum, N);
    k_scan2<<<1, 256, 0, stream>>>(bsum, boff, NB_N);
    k_scan3<<<NB_N, 256, 0, stream>>>(row_ptr, cursor, boff, N, E);
    k_scatter<<<NB_E, 256, 0, stream>>>(edge_index, edge_types, edge_attr, dflag, cursor, pbuf, fbuf, E);
    k_convw<<<1, 256, 0, stream>>>(W1, W2, dflag, Wf1, Wf2);

    k_t1<<<NB_N, 256, 0, stream>>>(node_emb, Wf1, q1, k1, dflag, xt1, dq1, dk1, N);
    k_gather<15><<<NB_G, 256, 0, stream>>>(row_ptr, pbuf, fbuf, dq1, dk1, xt1, We1, e1, b1, dflag, out1, N);
    k_bnstats<15><<<NB_N, 256, 0, stream>>>(out1, stats1, N);
    k_t2<<<NB_N, 256, 0, stream>>>(out1, stats1, g1, beta1, Wf2, q2, k2, dflag, xt2, dq2, dk2, N);
    k_gather<10><<<NB_G, 256, 0, stream>>>(row_ptr, pbuf, fbuf, dq2, dk2, xt2, We2, e2, b2, dflag, out2, N);
    k_bnstats<10><<<NB_N, 256, 0, stream>>>(out2, stats2, N);
    k_head<<<NB_N, 256, 0, stream>>>(out2, stats2, g2, beta2, w_head, b_head, dflag, d_out, N);
}

// Round 3
// 569.104 us; speedup vs baseline: 1.0652x; 1.0652x over previous
//
#include <hip/hip_runtime.h>

// RGAT 2-layer + BN/ELU + head for MI355X (gfx950).
// Float inputs may be bf16 OR fp32 (runtime-detected); ints are int32.
// Internal compute fp32 in workspace. Output stored in detected float width.

typedef unsigned short ushort_t;
typedef unsigned int uint_t;

#define NEG_SLOPE 0.2f
#define BN_EPS 1e-5f
#define CAP 256   // per-node LDS alpha cache (recompute fallback beyond)

__device__ __forceinline__ float bf2f(ushort_t u) {
    return __uint_as_float(((uint_t)u) << 16);
}
__device__ __forceinline__ ushort_t f2bf(float f) {
    uint_t x = __float_as_uint(f);
    x += 0x7FFFu + ((x >> 16) & 1u);   // round-to-nearest-even
    return (ushort_t)(x >> 16);
}
// generic float load: bf16 (isb=1) or fp32 (isb=0)
__device__ __forceinline__ float loadf(const void* p, int i, int isb) {
    return isb ? bf2f(((const ushort_t*)p)[i]) : ((const float*)p)[i];
}

// ---------------- input dtype detection ----------------
__global__ void k_detect(const uint_t* __restrict__ x, int* __restrict__ flag) {
    int t = threadIdx.x;
    uint_t u = x[t * 37];
    uint_t lo_exp = (u >> 7) & 0xFF;
    int like = (lo_exp >= 96 && lo_exp <= 150) ? 1 : 0;
    __shared__ int cnt;
    if (t == 0) cnt = 0;
    __syncthreads();
    atomicAdd(&cnt, like);
    __syncthreads();
    if (t == 0) flag[0] = (cnt > 192) ? 1 : 0;
}

// ---------------- CSR build ----------------
__global__ void k_count(const int* __restrict__ ei, int* __restrict__ deg, int E) {
    int e = blockIdx.x * 256 + threadIdx.x;
    if (e < E) atomicAdd(&deg[ei[E + e]], 1);
}

__global__ void k_scan1(const int* __restrict__ deg, int* __restrict__ part,
                        int* __restrict__ bsum, int N) {
    __shared__ int s[256];
    int t = threadIdx.x;
    int i = blockIdx.x * 256 + t;
    int v = (i < N) ? deg[i] : 0;
    s[t] = v; __syncthreads();
    for (int off = 1; off < 256; off <<= 1) {
        int x = (t >= off) ? s[t - off] : 0;
        __syncthreads();
        s[t] += x;
        __syncthreads();
    }
    if (i < N) part[i] = s[t] - v;           // exclusive within block
    if (t == 255) bsum[blockIdx.x] = s[255]; // block total
}

__global__ void k_scan2(const int* __restrict__ bsum, int* __restrict__ boff, int NB) {
    __shared__ int s[256];
    int t = threadIdx.x;
    int v = (t < NB) ? bsum[t] : 0;
    s[t] = v; __syncthreads();
    for (int off = 1; off < 256; off <<= 1) {
        int x = (t >= off) ? s[t - off] : 0;
        __syncthreads();
        s[t] += x;
        __syncthreads();
    }
    if (t < NB) boff[t] = s[t] - v;
}

__global__ void k_scan3(int* __restrict__ row, int* __restrict__ cursor,
                        const int* __restrict__ boff, int N, int E) {
    int i = blockIdx.x * 256 + threadIdx.x;
    if (i < N) {
        int v = row[i] + boff[blockIdx.x];
        row[i] = v;
        cursor[i] = v;
    }
    if (i == 0) row[N] = E;
}

// single 8B record per edge: {src|etype<<20, eattr bits} — one scattered line
__global__ void k_scatter(const int* __restrict__ ei, const int* __restrict__ et,
                          const void* __restrict__ ea, const int* __restrict__ flag,
                          int* __restrict__ cursor, int2* __restrict__ ebuf, int E) {
    int isb = flag[0];
    int e = blockIdx.x * 256 + threadIdx.x;
    if (e < E) {
        int d = ei[E + e];
        int pos = atomicAdd(&cursor[d], 1);
        int2 rec;
        rec.x = ei[e] | (et[e] << 20);   // src < 2^20, etype < 4
        rec.y = __float_as_int(loadf(ea, e, isb));
        ebuf[pos] = rec;
    }
}

// ---------------- weight pre-transpose to fp32 [f][r*O+o] ----------------
__global__ void k_convw(const void* __restrict__ W1, const void* __restrict__ W2,
                        const int* __restrict__ flag,
                        float* __restrict__ Wf1, float* __restrict__ Wf2) {
    int isb = flag[0];
    int t = threadIdx.x;
    for (int idx = t; idx < 128 * 60; idx += 256) {
        int f = idx / 60, j = idx % 60, r = j / 15, o = j % 15;
        Wf1[idx] = loadf(W1, (r * 128 + f) * 15 + o, isb);
    }
    for (int idx = t; idx < 15 * 40; idx += 256) {
        int f = idx / 40, j = idx % 40, r = j / 10, o = j % 10;
        Wf2[idx] = loadf(W2, (r * 15 + f) * 10 + o, isb);
    }
}

// ---------------- layer-1 transform: xt1[n][r*16+o] (64B rows), dotq/dotk ----------------
__global__ __launch_bounds__(256) void k_t1(const void* __restrict__ xin,
                                            const float* __restrict__ Wf,
                                            const void* __restrict__ qb,
                                            const void* __restrict__ kb,
                                            const int* __restrict__ flag,
                                            float* __restrict__ xt,
                                            float* __restrict__ dq,
                                            float* __restrict__ dk, int N) {
    int isb = flag[0];
    int n = blockIdx.x * 256 + threadIdx.x;
    if (n >= N) return;
    float acc[60];
#pragma unroll
    for (int j = 0; j < 60; ++j) acc[j] = 0.f;
    if (isb) {
        const uint4* x4 = reinterpret_cast<const uint4*>((const ushort_t*)xin + (size_t)n * 128);
        for (int c = 0; c < 16; ++c) {       // 16 chunks x 8 bf16
            uint4 u = x4[c];
            uint_t w[4] = {u.x, u.y, u.z, u.w};
#pragma unroll
            for (int h = 0; h < 4; ++h) {
                float x0 = __uint_as_float(w[h] << 16);
                float x1 = __uint_as_float(w[h] & 0xFFFF0000u);
                const float* wp = Wf + (c * 8 + h * 2) * 60;
#pragma unroll
                for (int o = 0; o < 60; ++o) acc[o] += x0 * wp[o];
#pragma unroll
                for (int o = 0; o < 60; ++o) acc[o] += x1 * wp[60 + o];
            }
        }
    } else {
        const float4* x4 = reinterpret_cast<const float4*>((const float*)xin + (size_t)n * 128);
        for (int c = 0; c < 32; ++c) {       // 32 chunks x 4 fp32
            float4 u = x4[c];
            const float* wp = Wf + c * 4 * 60;
#pragma unroll
            for (int o = 0; o < 60; ++o) acc[o] += u.x * wp[o];
#pragma unroll
            for (int o = 0; o < 60; ++o) acc[o] += u.y * wp[60 + o];
#pragma unroll
            for (int o = 0; o < 60; ++o) acc[o] += u.z * wp[120 + o];
#pragma unroll
            for (int o = 0; o < 60; ++o) acc[o] += u.w * wp[180 + o];
        }
    }
    float qf[15], kf[15];
#pragma unroll
    for (int o = 0; o < 15; ++o) { qf[o] = loadf(qb, o, isb); kf[o] = loadf(kb, o, isb); }
#pragma unroll
    for (int r = 0; r < 4; ++r) {
        float a = 0.f, b = 0.f;
#pragma unroll
        for (int o = 0; o < 15; ++o) { a += acc[r * 15 + o] * qf[o]; b += acc[r * 15 + o] * kf[o]; }
        dq[n * 4 + r] = a;
        dk[n * 4 + r] = b;
    }
#pragma unroll
    for (int r = 0; r < 4; ++r) {
#pragma unroll
        for (int o = 0; o < 15; ++o) xt[(size_t)n * 64 + r * 16 + o] = acc[r * 15 + o];
        xt[(size_t)n * 64 + r * 16 + 15] = 0.f;   // pad lane -> contributes 0
    }
}

// ---------------- layer-2 transform: BN1+ELU fused, xt2[n][r*16+o] ----------------
__global__ __launch_bounds__(256) void k_t2(const float* __restrict__ in,
                                            const float* __restrict__ stats,
                                            const void* __restrict__ g,
                                            const void* __restrict__ beta,
                                            const float* __restrict__ Wf,
                                            const void* __restrict__ qb,
                                            const void* __restrict__ kb,
                                            const int* __restrict__ flag,
                                            float* __restrict__ xt,
                                            float* __restrict__ dq,
                                            float* __restrict__ dk, int N) {
    int isb = flag[0];
    int n = blockIdx.x * 256 + threadIdx.x;
    if (n >= N) return;
    float invN = 1.f / (float)N;
    float v[15];
#pragma unroll
    for (int c = 0; c < 15; ++c) {
        float mean = stats[c] * invN;
        float var = stats[16 + c] * invN - mean * mean;
        float inv = rsqrtf(var + BN_EPS);
        float h = (in[(size_t)n * 15 + c] - mean) * inv * loadf(g, c, isb) + loadf(beta, c, isb);
        v[c] = h > 0.f ? h : expm1f(h);  // ELU
    }
    float acc[40];
#pragma unroll
    for (int j = 0; j < 40; ++j) acc[j] = 0.f;
#pragma unroll
    for (int f = 0; f < 15; ++f) {
        const float* wp = Wf + f * 40;
#pragma unroll
        for (int o = 0; o < 40; ++o) acc[o] += v[f] * wp[o];
    }
    float qf[10], kf[10];
#pragma unroll
    for (int o = 0; o < 10; ++o) { qf[o] = loadf(qb, o, isb); kf[o] = loadf(kb, o, isb); }
#pragma unroll
    for (int r = 0; r < 4; ++r) {
        float a = 0.f, b = 0.f;
#pragma unroll
        for (int o = 0; o < 10; ++o) { a += acc[r * 10 + o] * qf[o]; b += acc[r * 10 + o] * kf[o]; }
        dq[n * 4 + r] = a;
        dk[n * 4 + r] = b;
    }
#pragma unroll
    for (int r = 0; r < 4; ++r) {
#pragma unroll
        for (int o = 0; o < 10; ++o) xt[(size_t)n * 64 + r * 16 + o] = acc[r * 10 + o];
#pragma unroll
        for (int o = 10; o < 16; ++o) xt[(size_t)n * 64 + r * 16 + o] = 0.f;
    }
}

// ---------------- per-node gather: softmax + weighted aggregation ----------------
// One 64-lane wave per node (4 waves/block). Phase A: online softmax, alpha+pk
// cached in LDS. Phase B: 4 edge-groups x 16 channel-lanes, one 64B line/edge.
template <int O>
__global__ __launch_bounds__(256) void k_gather(const int* __restrict__ row_ptr,
                                                const int2* __restrict__ ebuf,
                                                const float* __restrict__ dq,
                                                const float* __restrict__ dk,
                                                const float* __restrict__ xt,
                                                const void* __restrict__ Web,
                                                const void* __restrict__ eb,
                                                const void* __restrict__ bb,
                                                const int* __restrict__ flag,
                                                float* __restrict__ out, int N) {
    __shared__ float sA[4 * CAP];
    __shared__ int   sP[4 * CAP];
    int isb = flag[0];
    int lane = threadIdx.x & 63;
    int w = threadIdx.x >> 6;
    int n = blockIdx.x * 4 + w;
    if (n >= N) return;
    float c = 0.f;  // scalar (We . e)
#pragma unroll
    for (int o = 0; o < O; ++o) c += loadf(Web, o, isb) * loadf(eb, o, isb);
    int start = row_ptr[n], end = row_ptr[n + 1];
    float dq0 = dq[n * 4], dq1 = dq[n * 4 + 1], dq2 = dq[n * 4 + 2], dq3 = dq[n * 4 + 3];

    // Phase A: online softmax; cache alpha + packed edge in LDS
    float m = -1e30f, s = 0.f;
    for (int p = start + lane; p < end; p += 64) {
        int2 rec = ebuf[p];
        int sr = rec.x & 0xFFFFF, et = rec.x >> 20;
        float dqv = et < 2 ? (et == 0 ? dq0 : dq1) : (et == 2 ? dq2 : dq3);
        float a = dqv + dk[sr * 4 + et] + c * __int_as_float(rec.y);
        a = a > 0.f ? a : NEG_SLOPE * a;
        int idx = p - start;
        if (idx < CAP) { sA[w * CAP + idx] = a; sP[w * CAP + idx] = rec.x; }
        float mn = fmaxf(m, a);
        s = s * __expf(m - mn) + __expf(a - mn);
        m = mn;
    }
#pragma unroll
    for (int off = 32; off; off >>= 1) {
        float m2 = __shfl_xor(m, off, 64);
        float s2 = __shfl_xor(s, off, 64);
        float mn = fmaxf(m, m2);
        s = s * __expf(m - mn) + s2 * __expf(m2 - mn);
        m = mn;
    }
    float inv = 1.f / (s + 1e-16f);

    // Phase B: weighted aggregation, channels across lanes (padded 64B rows)
    int g = lane >> 4, ch = lane & 15;
    float acc = 0.f;
    for (int p = start + g; p < end; p += 4) {
        int idx = p - start;
        int pk; float a;
        if (idx < CAP) {
            pk = sP[w * CAP + idx];
            a = sA[w * CAP + idx];
        } else {
            int2 rec = ebuf[p];
            pk = rec.x;
            int sr = pk & 0xFFFFF, et = pk >> 20;
            float dqv = et < 2 ? (et == 0 ? dq0 : dq1) : (et == 2 ? dq2 : dq3);
            a = dqv + dk[sr * 4 + et] + c * __int_as_float(rec.y);
            a = a > 0.f ? a : NEG_SLOPE * a;
        }
        float coeff = __expf(a - m) * inv;
        int sr = pk & 0xFFFFF, et = pk >> 20;
        acc += coeff * xt[(size_t)(sr * 4 + et) * 16 + ch];
    }
    acc += __shfl_xor(acc, 16, 64);
    acc += __shfl_xor(acc, 32, 64);
    if (lane < O) out[(size_t)n * O + lane] = acc + loadf(bb, lane, isb);
}

// ---------------- BN batch statistics (sum, sumsq per channel) ----------------
template <int C>
__global__ __launch_bounds__(256) void k_bnstats(const float* __restrict__ in,
                                                 float* __restrict__ S, int N) {
    int t = threadIdx.x;
    int ch = t & 15, rg = t >> 4;
    float s1 = 0.f, s2 = 0.f;
    int row0 = blockIdx.x * 256;
    int rowEnd = row0 + 256;
    if (rowEnd > N) rowEnd = N;
    if (ch < C) {
        for (int r = row0 + rg; r < rowEnd; r += 16) {
            float v = in[(size_t)r * C + ch];
            s1 += v;
            s2 += v * v;
        }
    }
    __shared__ float L1[256], L2[256];
    L1[t] = s1; L2[t] = s2;
    __syncthreads();
    for (int k = 128; k >= 16; k >>= 1) {
        if (t < k) { L1[t] += L1[t + k]; L2[t] += L2[t + k]; }
        __syncthreads();
    }
    if (t < C) {
        atomicAdd(&S[t], L1[t]);
        atomicAdd(&S[16 + t], L2[t]);
    }
}

// ---------------- BN2 + ELU + head, bf16-or-fp32 output ----------------
__global__ __launch_bounds__(256) void k_head(const float* __restrict__ in,
                                              const float* __restrict__ stats,
                                              const void* __restrict__ g,
                                              const void* __restrict__ beta,
                                              const void* __restrict__ wh,
                                              const void* __restrict__ bh,
                                              const int* __restrict__ flag,
                                              void* __restrict__ out, int N) {
    int isb = flag[0];
    int n = blockIdx.x * 256 + threadIdx.x;
    if (n >= N) return;
    float invN = 1.f / (float)N;
    float r = loadf(bh, 0, isb);
#pragma unroll
    for (int c = 0; c < 10; ++c) {
        float mean = stats[c] * invN;
        float var = stats[16 + c] * invN - mean * mean;
        float inv = rsqrtf(var + BN_EPS);
        float h = (in[(size_t)n * 10 + c] - mean) * inv * loadf(g, c, isb) + loadf(beta, c, isb);
        float e = h > 0.f ? h : expm1f(h);
        r += e * loadf(wh, c, isb);
    }
    if (isb) ((ushort_t*)out)[n] = f2bf(r);
    else     ((float*)out)[n] = r;
}

extern "C" void kernel_launch(void* const* d_in, const int* in_sizes, int n_in,
                              void* d_out, int out_size, void* d_ws, size_t ws_size,
                              hipStream_t stream) {
    const void* node_emb  = d_in[0];
    const int*  edge_index = (const int*)d_in[1];
    const int*  edge_types = (const int*)d_in[2];
    const void* edge_attr = d_in[3];
    const void* W1  = d_in[4];
    const void* q1  = d_in[5];
    const void* k1  = d_in[6];
    const void* e1  = d_in[7];
    const void* We1 = d_in[8];
    const void* b1  = d_in[9];
    const void* W2  = d_in[10];
    const void* q2  = d_in[11];
    const void* k2  = d_in[12];
    const void* e2  = d_in[13];
    const void* We2 = d_in[14];
    const void* b2  = d_in[15];
    const void* g1  = d_in[16];
    const void* beta1 = d_in[17];
    const void* g2  = d_in[18];
    const void* beta2 = d_in[19];
    const void* w_head = d_in[20];
    const void* b_head = d_in[21];

    int N = in_sizes[0] / 128;
    int E = in_sizes[1] / 2;

    char* ws = (char*)d_ws;
    size_t off = 0;
    auto alloc = [&](size_t bytes) -> void* {
        void* p = ws + off;
        off = (off + bytes + 255) & ~(size_t)255;
        return p;
    };
    int*   row_ptr = (int*)alloc(((size_t)N + 1) * 4);
    int*   deg     = (int*)alloc((size_t)N * 4);
    int*   cursor  = (int*)alloc((size_t)N * 4);
    int*   bsum    = (int*)alloc(256 * 4);
    int*   boff    = (int*)alloc(256 * 4);
    int*   dflag   = (int*)alloc(256);
    int2*  ebuf    = (int2*)alloc((size_t)E * 8);
    float* xt1     = (float*)alloc((size_t)N * 64 * 4);   // padded 64B rows; layer2 overlays
    float* dq1     = (float*)alloc((size_t)N * 16);
    float* dk1     = (float*)alloc((size_t)N * 16);
    float* out1    = (float*)alloc((size_t)N * 15 * 4);   // out2 overlays
    float* stats1  = (float*)alloc(128);
    float* stats2  = (float*)alloc(128);
    float* Wf1     = (float*)alloc(7680 * 4);
    float* Wf2     = (float*)alloc(600 * 4);
    // overlays (lifetimes disjoint):
    float* xt2  = xt1;
    float* dq2  = dq1;
    float* dk2  = dk1;
    float* out2 = out1;

    hipMemsetAsync(deg, 0, (size_t)N * 4, stream);
    hipMemsetAsync(stats1, 0, 128, stream);
    hipMemsetAsync(stats2, 0, 128, stream);

    int NB_N = (N + 255) / 256;
    int NB_E = (E + 255) / 256;
    int NB_G = (N + 3) / 4;

    k_detect<<<1, 256, 0, stream>>>((const uint_t*)node_emb, dflag);
    k_count<<<NB_E, 256, 0, stream>>>(edge_index, deg, E);
    k_scan1<<<NB_N, 256, 0, stream>>>(deg, row_ptr, bsum, N);
    k_scan2<<<1, 256, 0, stream>>>(bsum, boff, NB_N);
    k_scan3<<<NB_N, 256, 0, stream>>>(row_ptr, cursor, boff, N, E);
    k_scatter<<<NB_E, 256, 0, stream>>>(edge_index, edge_types, edge_attr, dflag, cursor, ebuf, E);
    k_convw<<<1, 256, 0, stream>>>(W1, W2, dflag, Wf1, Wf2);

    k_t1<<<NB_N, 256, 0, stream>>>(node_emb, Wf1, q1, k1, dflag, xt1, dq1, dk1, N);
    k_gather<15><<<NB_G, 256, 0, stream>>>(row_ptr, ebuf, dq1, dk1, xt1, We1, e1, b1, dflag, out1, N);
    k_bnstats<15><<<NB_N, 256, 0, stream>>>(out1, stats1, N);
    k_t2<<<NB_N, 256, 0, stream>>>(out1, stats1, g1, beta1, Wf2, q2, k2, dflag, xt2, dq2, dk2, N);
    k_gather<10><<<NB_G, 256, 0, stream>>>(row_ptr, ebuf, dq2, dk2, xt2, We2, e2, b2, dflag, out2, N);
    k_bnstats<10><<<NB_N, 256, 0, stream>>>(out2, stats2, N);
    k_head<<<NB_N, 256, 0, stream>>>(out2, stats2, g2, beta2, w_head, b_head, dflag, d_out, N);
}

// Round 4
// 429.072 us; speedup vs baseline: 1.4129x; 1.3264x over previous
//
#include <hip/hip_runtime.h>

// RGAT 2-layer + BN/ELU + head for MI355X (gfx950).
// Float inputs may be bf16 OR fp32 (runtime-detected); ints are int32.
// Internal compute fp32 in workspace. Output stored in detected float width.
//
// CSR build strategy (round 4): random-destination scatter was costing
// 64B HBM write per 8B record (partial-line writebacks from many XCDs).
// Replaced with 512-bucket LDS-staged partition (coalesced run flushes)
// + per-bucket CSR finalize (single-block-local random writes).

typedef unsigned short ushort_t;
typedef unsigned int uint_t;

#define NEG_SLOPE 0.2f
#define BN_EPS 1e-5f
#define CAP 256     // per-node LDS alpha cache in gather (recompute fallback)
#define NBUCK 512   // partition buckets

__device__ __forceinline__ float bf2f(ushort_t u) {
    return __uint_as_float(((uint_t)u) << 16);
}
__device__ __forceinline__ ushort_t f2bf(float f) {
    uint_t x = __float_as_uint(f);
    x += 0x7FFFu + ((x >> 16) & 1u);   // round-to-nearest-even
    return (ushort_t)(x >> 16);
}
// generic float load: bf16 (isb=1) or fp32 (isb=0)
__device__ __forceinline__ float loadf(const void* p, int i, int isb) {
    return isb ? bf2f(((const ushort_t*)p)[i]) : ((const float*)p)[i];
}

// ---------------- input dtype detection ----------------
__global__ void k_detect(const uint_t* __restrict__ x, int* __restrict__ flag) {
    int t = threadIdx.x;
    uint_t u = x[t * 37];
    uint_t lo_exp = (u >> 7) & 0xFF;
    int like = (lo_exp >= 96 && lo_exp <= 150) ? 1 : 0;
    __shared__ int cnt;
    if (t == 0) cnt = 0;
    __syncthreads();
    atomicAdd(&cnt, like);
    __syncthreads();
    if (t == 0) flag[0] = (cnt > 192) ? 1 : 0;
}

// ---------------- bucket histogram ----------------
__global__ __launch_bounds__(256) void k_hist(const int* __restrict__ ei,
                                              int* __restrict__ hist, int E, int npb) {
    __shared__ int h[NBUCK];
    int t = threadIdx.x;
    for (int i = t; i < NBUCK; i += 256) h[i] = 0;
    __syncthreads();
    int e0 = blockIdx.x * 4096;
    for (int i = 0; i < 16; ++i) {
        int e = e0 + i * 256 + t;
        if (e < E) atomicAdd(&h[ei[E + e] / npb], 1);
    }
    __syncthreads();
    for (int i = t; i < NBUCK; i += 256) {
        int c = h[i];
        if (c) atomicAdd(&hist[i], c);
    }
}

// ---------------- bucket base scan ----------------
__global__ __launch_bounds__(NBUCK) void k_bscan(const int* __restrict__ hist,
                                                 int* __restrict__ base,
                                                 int* __restrict__ cursor,
                                                 int* __restrict__ row_ptr,
                                                 int N, int E) {
    __shared__ int sc[NBUCK];
    int t = threadIdx.x;
    int v = hist[t];
    sc[t] = v;
    __syncthreads();
    for (int off = 1; off < NBUCK; off <<= 1) {
        int x = (t >= off) ? sc[t - off] : 0;
        __syncthreads();
        sc[t] += x;
        __syncthreads();
    }
    int ex = sc[t] - v;
    base[t] = ex;
    cursor[t] = ex;
    if (t == NBUCK - 1) { base[NBUCK] = E; row_ptr[N] = E; }
}

// ---------------- LDS-staged bucket partition ----------------
// tmp record: x = src | et<<23 | ldst<<25 ; y = eattr fp32 bits
__global__ __launch_bounds__(512) void k_bucket(const int* __restrict__ ei,
                                                const int* __restrict__ et,
                                                const void* __restrict__ ea,
                                                const int* __restrict__ flag,
                                                int* __restrict__ bcur,
                                                int2* __restrict__ tmp,
                                                int E, int npb) {
    extern __shared__ int2 srec[];           // 8192 records = 64 KB
    __shared__ int cnt[NBUCK];
    __shared__ int lofs[NBUCK + 1];
    __shared__ int gpos[NBUCK];
    int t = threadIdx.x;
    int isb = flag[0];
    cnt[t] = 0;
    __syncthreads();
    int e0 = blockIdx.x * 8192;
    // pass 1: count
    for (int i = 0; i < 16; ++i) {
        int e = e0 + i * 512 + t;
        if (e < E) atomicAdd(&cnt[ei[E + e] / npb], 1);
    }
    __syncthreads();
    int myc = cnt[t];
    // inclusive scan in place
    for (int off = 1; off < NBUCK; off <<= 1) {
        int v = (t >= off) ? cnt[t - off] : 0;
        __syncthreads();
        cnt[t] += v;
        __syncthreads();
    }
    lofs[t] = cnt[t] - myc;
    if (t == NBUCK - 1) lofs[NBUCK] = cnt[NBUCK - 1];
    __syncthreads();
    cnt[t] = lofs[t];   // reuse as local cursor
    __syncthreads();
    // pass 2: place into LDS grouped by bucket
    for (int i = 0; i < 16; ++i) {
        int e = e0 + i * 512 + t;
        if (e < E) {
            int d = ei[E + e];
            int b = d / npb;
            int ldst = d - b * npb;
            int idx = atomicAdd(&cnt[b], 1);
            int2 r;
            r.x = (int)((uint_t)ei[e] | ((uint_t)et[e] << 23) | ((uint_t)ldst << 25));
            r.y = __float_as_int(loadf(ea, e, isb));
            srec[idx] = r;
        }
    }
    __syncthreads();
    // reserve global ranges (one atomic per bucket per block)
    int c_b = lofs[t + 1] - lofs[t];
    gpos[t] = atomicAdd(&bcur[t], c_b);
    __syncthreads();
    // flush: contiguous runs per bucket (binary search slot -> bucket)
    int total = lofs[NBUCK];
    for (int i = t; i < total; i += 512) {
        int lo = 0, hi = NBUCK - 1;
        while (lo < hi) {
            int mid = (lo + hi + 1) >> 1;
            if (lofs[mid] <= i) lo = mid; else hi = mid - 1;
        }
        tmp[gpos[lo] + (i - lofs[lo])] = srec[i];
    }
}

// ---------------- per-bucket CSR finalize ----------------
__global__ __launch_bounds__(256) void k_b2csr(const int2* __restrict__ tmp,
                                               const int* __restrict__ base,
                                               int* __restrict__ row_ptr,
                                               int2* __restrict__ ebuf,
                                               int N, int npb) {
    __shared__ int cnt[128];
    __shared__ int lofs[129];
    int b = blockIdx.x, t = threadIdx.x;
    int s0 = base[b], s1 = base[b + 1];
    if (t < 128) cnt[t] = 0;
    __syncthreads();
    for (int p = s0 + t; p < s1; p += 256) {
        uint_t x = (uint_t)tmp[p].x;
        atomicAdd(&cnt[(x >> 25) & 0x7F], 1);
    }
    __syncthreads();
    int myc = (t < 128) ? cnt[t] : 0;
    for (int off = 1; off < 128; off <<= 1) {
        int v = (t >= off && t < 128) ? cnt[t - off] : 0;
        __syncthreads();
        if (t < 128) cnt[t] += v;
        __syncthreads();
    }
    if (t < 128) {
        lofs[t] = cnt[t] - myc;
        if (t == 127) lofs[128] = cnt[127];
    }
    __syncthreads();
    int node0 = b * npb;
    if (t < npb && node0 + t < N) row_ptr[node0 + t] = s0 + lofs[t];
    if (t < 128) cnt[t] = lofs[t];   // reuse as cursor
    __syncthreads();
    for (int p = s0 + t; p < s1; p += 256) {
        int2 r = tmp[p];
        uint_t x = (uint_t)r.x;
        int ldst = (x >> 25) & 0x7F;
        int idx = atomicAdd(&cnt[ldst], 1);
        int2 o;
        o.x = (int)(x & 0x7FFFFF) | (((int)(x >> 23) & 3) << 20);  // src | et<<20
        o.y = r.y;
        ebuf[s0 + idx] = o;
    }
}

// ---------------- weight pre-transpose to fp32 [f][r*O+o] ----------------
__global__ void k_convw(const void* __restrict__ W1, const void* __restrict__ W2,
                        const int* __restrict__ flag,
                        float* __restrict__ Wf1, float* __restrict__ Wf2) {
    int isb = flag[0];
    int t = threadIdx.x;
    for (int idx = t; idx < 128 * 60; idx += 256) {
        int f = idx / 60, j = idx % 60, r = j / 15, o = j % 15;
        Wf1[idx] = loadf(W1, (r * 128 + f) * 15 + o, isb);
    }
    for (int idx = t; idx < 15 * 40; idx += 256) {
        int f = idx / 40, j = idx % 40, r = j / 10, o = j % 10;
        Wf2[idx] = loadf(W2, (r * 15 + f) * 10 + o, isb);
    }
}

// ---------------- layer-1 transform: xt1[n][r*16+o] (64B rows), dotq/dotk ----------------
__global__ __launch_bounds__(256) void k_t1(const void* __restrict__ xin,
                                            const float* __restrict__ Wf,
                                            const void* __restrict__ qb,
                                            const void* __restrict__ kb,
                                            const int* __restrict__ flag,
                                            float* __restrict__ xt,
                                            float* __restrict__ dq,
                                            float* __restrict__ dk, int N) {
    int isb = flag[0];
    int n = blockIdx.x * 256 + threadIdx.x;
    if (n >= N) return;
    float acc[60];
#pragma unroll
    for (int j = 0; j < 60; ++j) acc[j] = 0.f;
    if (isb) {
        const uint4* x4 = reinterpret_cast<const uint4*>((const ushort_t*)xin + (size_t)n * 128);
        for (int c = 0; c < 16; ++c) {       // 16 chunks x 8 bf16
            uint4 u = x4[c];
            uint_t w[4] = {u.x, u.y, u.z, u.w};
#pragma unroll
            for (int h = 0; h < 4; ++h) {
                float x0 = __uint_as_float(w[h] << 16);
                float x1 = __uint_as_float(w[h] & 0xFFFF0000u);
                const float* wp = Wf + (c * 8 + h * 2) * 60;
#pragma unroll
                for (int o = 0; o < 60; ++o) acc[o] += x0 * wp[o];
#pragma unroll
                for (int o = 0; o < 60; ++o) acc[o] += x1 * wp[60 + o];
            }
        }
    } else {
        const float4* x4 = reinterpret_cast<const float4*>((const float*)xin + (size_t)n * 128);
        for (int c = 0; c < 32; ++c) {       // 32 chunks x 4 fp32
            float4 u = x4[c];
            const float* wp = Wf + c * 4 * 60;
#pragma unroll
            for (int o = 0; o < 60; ++o) acc[o] += u.x * wp[o];
#pragma unroll
            for (int o = 0; o < 60; ++o) acc[o] += u.y * wp[60 + o];
#pragma unroll
            for (int o = 0; o < 60; ++o) acc[o] += u.z * wp[120 + o];
#pragma unroll
            for (int o = 0; o < 60; ++o) acc[o] += u.w * wp[180 + o];
        }
    }
    float qf[15], kf[15];
#pragma unroll
    for (int o = 0; o < 15; ++o) { qf[o] = loadf(qb, o, isb); kf[o] = loadf(kb, o, isb); }
#pragma unroll
    for (int r = 0; r < 4; ++r) {
        float a = 0.f, b = 0.f;
#pragma unroll
        for (int o = 0; o < 15; ++o) { a += acc[r * 15 + o] * qf[o]; b += acc[r * 15 + o] * kf[o]; }
        dq[n * 4 + r] = a;
        dk[n * 4 + r] = b;
    }
#pragma unroll
    for (int r = 0; r < 4; ++r) {
#pragma unroll
        for (int o = 0; o < 15; ++o) xt[(size_t)n * 64 + r * 16 + o] = acc[r * 15 + o];
        xt[(size_t)n * 64 + r * 16 + 15] = 0.f;   // pad lane -> contributes 0
    }
}

// ---------------- layer-2 transform: BN1+ELU fused, xt2[n][r*16+o] ----------------
__global__ __launch_bounds__(256) void k_t2(const float* __restrict__ in,
                                            const float* __restrict__ stats,
                                            const void* __restrict__ g,
                                            const void* __restrict__ beta,
                                            const float* __restrict__ Wf,
                                            const void* __restrict__ qb,
                                            const void* __restrict__ kb,
                                            const int* __restrict__ flag,
                                            float* __restrict__ xt,
                                            float* __restrict__ dq,
                                            float* __restrict__ dk, int N) {
    int isb = flag[0];
    int n = blockIdx.x * 256 + threadIdx.x;
    if (n >= N) return;
    float invN = 1.f / (float)N;
    float v[15];
#pragma unroll
    for (int c = 0; c < 15; ++c) {
        float mean = stats[c] * invN;
        float var = stats[16 + c] * invN - mean * mean;
        float inv = rsqrtf(var + BN_EPS);
        float h = (in[(size_t)n * 15 + c] - mean) * inv * loadf(g, c, isb) + loadf(beta, c, isb);
        v[c] = h > 0.f ? h : expm1f(h);  // ELU
    }
    float acc[40];
#pragma unroll
    for (int j = 0; j < 40; ++j) acc[j] = 0.f;
#pragma unroll
    for (int f = 0; f < 15; ++f) {
        const float* wp = Wf + f * 40;
#pragma unroll
        for (int o = 0; o < 40; ++o) acc[o] += v[f] * wp[o];
    }
    float qf[10], kf[10];
#pragma unroll
    for (int o = 0; o < 10; ++o) { qf[o] = loadf(qb, o, isb); kf[o] = loadf(kb, o, isb); }
#pragma unroll
    for (int r = 0; r < 4; ++r) {
        float a = 0.f, b = 0.f;
#pragma unroll
        for (int o = 0; o < 10; ++o) { a += acc[r * 10 + o] * qf[o]; b += acc[r * 10 + o] * kf[o]; }
        dq[n * 4 + r] = a;
        dk[n * 4 + r] = b;
    }
#pragma unroll
    for (int r = 0; r < 4; ++r) {
#pragma unroll
        for (int o = 0; o < 10; ++o) xt[(size_t)n * 64 + r * 16 + o] = acc[r * 10 + o];
#pragma unroll
        for (int o = 10; o < 16; ++o) xt[(size_t)n * 64 + r * 16 + o] = 0.f;
    }
}

// ---------------- per-node gather: softmax + weighted aggregation ----------------
template <int O>
__global__ __launch_bounds__(256) void k_gather(const int* __restrict__ row_ptr,
                                                const int2* __restrict__ ebuf,
                                                const float* __restrict__ dq,
                                                const float* __restrict__ dk,
                                                const float* __restrict__ xt,
                                                const void* __restrict__ Web,
                                                const void* __restrict__ eb,
                                                const void* __restrict__ bb,
                                                const int* __restrict__ flag,
                                                float* __restrict__ out, int N) {
    __shared__ float sA[4 * CAP];
    __shared__ int   sP[4 * CAP];
    int isb = flag[0];
    int lane = threadIdx.x & 63;
    int w = threadIdx.x >> 6;
    int n = blockIdx.x * 4 + w;
    if (n >= N) return;
    float c = 0.f;  // scalar (We . e)
#pragma unroll
    for (int o = 0; o < O; ++o) c += loadf(Web, o, isb) * loadf(eb, o, isb);
    int start = row_ptr[n], end = row_ptr[n + 1];
    float dq0 = dq[n * 4], dq1 = dq[n * 4 + 1], dq2 = dq[n * 4 + 2], dq3 = dq[n * 4 + 3];

    // Phase A: online softmax; cache alpha + packed edge in LDS
    float m = -1e30f, s = 0.f;
    for (int p = start + lane; p < end; p += 64) {
        int2 rec = ebuf[p];
        int sr = rec.x & 0xFFFFF, et = rec.x >> 20;
        float dqv = et < 2 ? (et == 0 ? dq0 : dq1) : (et == 2 ? dq2 : dq3);
        float a = dqv + dk[sr * 4 + et] + c * __int_as_float(rec.y);
        a = a > 0.f ? a : NEG_SLOPE * a;
        int idx = p - start;
        if (idx < CAP) { sA[w * CAP + idx] = a; sP[w * CAP + idx] = rec.x; }
        float mn = fmaxf(m, a);
        s = s * __expf(m - mn) + __expf(a - mn);
        m = mn;
    }
#pragma unroll
    for (int off = 32; off; off >>= 1) {
        float m2 = __shfl_xor(m, off, 64);
        float s2 = __shfl_xor(s, off, 64);
        float mn = fmaxf(m, m2);
        s = s * __expf(m - mn) + s2 * __expf(m2 - mn);
        m = mn;
    }
    float inv = 1.f / (s + 1e-16f);

    // Phase B: weighted aggregation, channels across lanes (padded 64B rows)
    int g = lane >> 4, ch = lane & 15;
    float acc = 0.f;
    for (int p = start + g; p < end; p += 4) {
        int idx = p - start;
        int pk; float a;
        if (idx < CAP) {
            pk = sP[w * CAP + idx];
            a = sA[w * CAP + idx];
        } else {
            int2 rec = ebuf[p];
            pk = rec.x;
            int sr = pk & 0xFFFFF, et = pk >> 20;
            float dqv = et < 2 ? (et == 0 ? dq0 : dq1) : (et == 2 ? dq2 : dq3);
            a = dqv + dk[sr * 4 + et] + c * __int_as_float(rec.y);
            a = a > 0.f ? a : NEG_SLOPE * a;
        }
        float coeff = __expf(a - m) * inv;
        int sr = pk & 0xFFFFF, et = pk >> 20;
        acc += coeff * xt[(size_t)(sr * 4 + et) * 16 + ch];
    }
    acc += __shfl_xor(acc, 16, 64);
    acc += __shfl_xor(acc, 32, 64);
    if (lane < O) out[(size_t)n * O + lane] = acc + loadf(bb, lane, isb);
}

// ---------------- BN batch statistics (sum, sumsq per channel) ----------------
template <int C>
__global__ __launch_bounds__(256) void k_bnstats(const float* __restrict__ in,
                                                 float* __restrict__ S, int N) {
    int t = threadIdx.x;
    int ch = t & 15, rg = t >> 4;
    float s1 = 0.f, s2 = 0.f;
    int row0 = blockIdx.x * 256;
    int rowEnd = row0 + 256;
    if (rowEnd > N) rowEnd = N;
    if (ch < C) {
        for (int r = row0 + rg; r < rowEnd; r += 16) {
            float v = in[(size_t)r * C + ch];
            s1 += v;
            s2 += v * v;
        }
    }
    __shared__ float L1[256], L2[256];
    L1[t] = s1; L2[t] = s2;
    __syncthreads();
    for (int k = 128; k >= 16; k >>= 1) {
        if (t < k) { L1[t] += L1[t + k]; L2[t] += L2[t + k]; }
        __syncthreads();
    }
    if (t < C) {
        atomicAdd(&S[t], L1[t]);
        atomicAdd(&S[16 + t], L2[t]);
    }
}

// ---------------- BN2 + ELU + head, bf16-or-fp32 output ----------------
__global__ __launch_bounds__(256) void k_head(const float* __restrict__ in,
                                              const float* __restrict__ stats,
                                              const void* __restrict__ g,
                                              const void* __restrict__ beta,
                                              const void* __restrict__ wh,
                                              const void* __restrict__ bh,
                                              const int* __restrict__ flag,
                                              void* __restrict__ out, int N) {
    int isb = flag[0];
    int n = blockIdx.x * 256 + threadIdx.x;
    if (n >= N) return;
    float invN = 1.f / (float)N;
    float r = loadf(bh, 0, isb);
#pragma unroll
    for (int c = 0; c < 10; ++c) {
        float mean = stats[c] * invN;
        float var = stats[16 + c] * invN - mean * mean;
        float inv = rsqrtf(var + BN_EPS);
        float h = (in[(size_t)n * 10 + c] - mean) * inv * loadf(g, c, isb) + loadf(beta, c, isb);
        float e = h > 0.f ? h : expm1f(h);
        r += e * loadf(wh, c, isb);
    }
    if (isb) ((ushort_t*)out)[n] = f2bf(r);
    else     ((float*)out)[n] = r;
}

extern "C" void kernel_launch(void* const* d_in, const int* in_sizes, int n_in,
                              void* d_out, int out_size, void* d_ws, size_t ws_size,
                              hipStream_t stream) {
    const void* node_emb  = d_in[0];
    const int*  edge_index = (const int*)d_in[1];
    const int*  edge_types = (const int*)d_in[2];
    const void* edge_attr = d_in[3];
    const void* W1  = d_in[4];
    const void* q1  = d_in[5];
    const void* k1  = d_in[6];
    const void* e1  = d_in[7];
    const void* We1 = d_in[8];
    const void* b1  = d_in[9];
    const void* W2  = d_in[10];
    const void* q2  = d_in[11];
    const void* k2  = d_in[12];
    const void* e2  = d_in[13];
    const void* We2 = d_in[14];
    const void* b2  = d_in[15];
    const void* g1  = d_in[16];
    const void* beta1 = d_in[17];
    const void* g2  = d_in[18];
    const void* beta2 = d_in[19];
    const void* w_head = d_in[20];
    const void* b_head = d_in[21];

    int N = in_sizes[0] / 128;
    int E = in_sizes[1] / 2;
    int npb = (N + NBUCK - 1) / NBUCK;         // nodes per bucket (98)
    int nbuck = (N + npb - 1) / npb;           // used buckets (511)

    char* ws = (char*)d_ws;
    size_t off = 0;
    auto alloc = [&](size_t bytes) -> void* {
        void* p = ws + off;
        off = (off + bytes + 255) & ~(size_t)255;
        return p;
    };
    int*   row_ptr = (int*)alloc(((size_t)N + 1) * 4);
    int*   hist    = (int*)alloc((NBUCK) * 4);
    int*   bbase   = (int*)alloc((NBUCK + 1) * 4);
    int*   bcur    = (int*)alloc((NBUCK) * 4);
    int*   dflag   = (int*)alloc(256);
    int2*  ebuf    = (int2*)alloc((size_t)E * 8);
    // xt (padded 64B rows) overlays ebuf_tmp: tmp dead before k_t1 writes xt
    size_t big = (size_t)N * 64 * 4;
    if ((size_t)E * 8 > big) big = (size_t)E * 8;
    float* xt1     = (float*)alloc(big);
    int2*  etmp    = (int2*)xt1;
    float* dq1     = (float*)alloc((size_t)N * 16);
    float* dk1     = (float*)alloc((size_t)N * 16);
    float* out1    = (float*)alloc((size_t)N * 15 * 4);   // out2 overlays
    float* stats1  = (float*)alloc(128);
    float* stats2  = (float*)alloc(128);
    float* Wf1     = (float*)alloc(7680 * 4);
    float* Wf2     = (float*)alloc(600 * 4);
    // overlays (lifetimes disjoint):
    float* xt2  = xt1;
    float* dq2  = dq1;
    float* dk2  = dk1;
    float* out2 = out1;

    hipMemsetAsync(hist, 0, NBUCK * 4, stream);
    hipMemsetAsync(stats1, 0, 128, stream);
    hipMemsetAsync(stats2, 0, 128, stream);

    int NB_N = (N + 255) / 256;
    int NB_G = (N + 3) / 4;
    int NB_H = (E + 4095) / 4096;
    int NB_B = (E + 8191) / 8192;

    k_detect<<<1, 256, 0, stream>>>((const uint_t*)node_emb, dflag);
    k_hist<<<NB_H, 256, 0, stream>>>(edge_index, hist, E, npb);
    k_bscan<<<1, NBUCK, 0, stream>>>(hist, bbase, bcur, row_ptr, N, E);
    k_bucket<<<NB_B, 512, 8192 * sizeof(int2), stream>>>(edge_index, edge_types, edge_attr,
                                                         dflag, bcur, etmp, E, npb);
    k_b2csr<<<nbuck, 256, 0, stream>>>(etmp, bbase, row_ptr, ebuf, N, npb);
    k_convw<<<1, 256, 0, stream>>>(W1, W2, dflag, Wf1, Wf2);

    k_t1<<<NB_N, 256, 0, stream>>>(node_emb, Wf1, q1, k1, dflag, xt1, dq1, dk1, N);
    k_gather<15><<<NB_G, 256, 0, stream>>>(row_ptr, ebuf, dq1, dk1, xt1, We1, e1, b1, dflag, out1, N);
    k_bnstats<15><<<NB_N, 256, 0, stream>>>(out1, stats1, N);
    k_t2<<<NB_N, 256, 0, stream>>>(out1, stats1, g1, beta1, Wf2, q2, k2, dflag, xt2, dq2, dk2, N);
    k_gather<10><<<NB_G, 256, 0, stream>>>(row_ptr, ebuf, dq2, dk2, xt2, We2, e2, b2, dflag, out2, N);
    k_bnstats<10><<<NB_N, 256, 0, stream>>>(out2, stats2, N);
    k_head<<<NB_N, 256, 0, stream>>>(out2, stats2, g2, beta2, w_head, b_head, dflag, d_out, N);
}